// Round 9
// baseline (212.137 us; speedup 1.0000x reference)
//
#include <hip/hip_runtime.h>
#include <hip/hip_bf16.h>
#include <stdint.h>

// Problem: B=4, N=1024, C=768, H=12, hd=64.
// out_x = (attn(qx,kx,vx,+) + attn(qyo,kx,vx,-)) @ Wp^T + bp
// out_y = (attn(qy,ky,vx,+) + attn(qxo,ky,vx,-)) @ Wp^T + bp   (vy = vx!)
// qkv[b,n, j*768 + h*64 + d], j in {0:qo, 1:q, 2:k, 3:v}
// NOTE: w_qkv rows j=0 are pre-scaled by -0.125*log2(e), j=1 by +0.125*log2(e)
// in cvt_bf16, so attention scores emerge in the log2 domain with sign folded:
// softmax is exp2(s) directly for BOTH self and cross attends.

#define BB 4
#define NN 1024
#define CC 768
#define HH 12
#define HD 64

typedef unsigned short u16;
typedef short short8 __attribute__((ext_vector_type(8)));
typedef float f32x4 __attribute__((ext_vector_type(4)));

extern "C" __device__ float __ocml_native_exp2_f32(float);

__device__ __forceinline__ u16 f2bf(float f) {
  unsigned int u = __float_as_uint(f);
  return (u16)((u + 0x7fffu + ((u >> 16) & 1u)) >> 16);
}

__device__ __forceinline__ void load_lds16(const u16* g, u16* l) {
  __builtin_amdgcn_global_load_lds((__attribute__((address_space(1))) const void*)g,
                                   (__attribute__((address_space(3))) void*)l, 16, 0, 0);
}

// fp32 -> bf16 conversion: seg 0=x, 1=y, 2=w_qkv (query rows pre-scaled), 3=w_proj
__global__ __launch_bounds__(256)
void cvt_bf16(const float* __restrict__ x, const float* __restrict__ y,
              const float* __restrict__ wq, const float* __restrict__ wp,
              u16* __restrict__ xb, u16* __restrict__ yb,
              u16* __restrict__ wqb, u16* __restrict__ wpb)
{
  const int seg = blockIdx.y;
  const float* src = seg == 0 ? x : (seg == 1 ? y : (seg == 2 ? wq : wp));
  u16* dst = seg == 0 ? xb : (seg == 1 ? yb : (seg == 2 ? wqb : wpb));
  const int n = (seg == 3) ? 768 * 768 : ((seg == 2) ? 3072 * 768 : 4096 * 768);
  const int i = (blockIdx.x * 256 + threadIdx.x) * 8;
  if (i >= n) return;
  float sc = 1.0f;
  if (seg == 2) {
    const int row = i / 768;  // output feature p; j = p/768
    sc = (row < 768) ? -0.18033688f : (row < 1536 ? 0.18033688f : 1.0f);
  }
  float4 a = *(const float4*)(src + i);
  float4 b = *(const float4*)(src + i + 4);
  ushort4 u0 = {f2bf(a.x * sc), f2bf(a.y * sc), f2bf(a.z * sc), f2bf(a.w * sc)};
  ushort4 u1 = {f2bf(b.x * sc), f2bf(b.y * sc), f2bf(b.z * sc), f2bf(b.w * sc)};
  *(ushort4*)(dst + i) = u0;
  *(ushort4*)(dst + i + 4) = u1;
}

// MFMA GEMM v15: C[m,p] = A[m,:] . W[p,:] (+bias). 128x128 tile, BK=64,
// 8 waves (512 thr), wave -> 64x32 sub-tile (acc[4][2]=32 AGPRs; v14's
// occupancy fix). NEW:
//  (1) 2-phase double-buffered staging (v12-verified mechanism): prologue
//      stages K-step 0; each step issues step t+1's global_load_lds into the
//      other buffer BEFORE computing step t; ONE barrier per step (12 vs 24).
//      LDS 64 KB; residency unchanged (reg-capped 2 blocks/CU, 128 KB <= 160).
//  (2) SWZ: XCD-chunked grid for the QKV GEMM — each XCD gets a contiguous
//      (m-tiles x col-tiles) chunk sized ~L2 (z=0: 16m x 6col -> A 3.1 MB +
//      W 1.2 MB; z=1: 8m x 9col -> 3.4 MB), attacking the 3.2x HBM overfetch
//      (FETCH 56.4 MB vs 17.3 MB unique). Bijective; z=1 early-out is
//      block-uniform (before any barrier).
// NZ1: column limit for blockIdx.z==1 (qkv_y's v-block j=3 is never read).
// VSPLIT: z==0, n0 in [2304,3072): epilogue writes VT directly (transposed +
// key-permuted, v11-verified) instead of C.
template<int NP, bool BF16OUT, bool BIAS, int NZ1, bool VSPLIT, bool SWZ>
__global__ __launch_bounds__(512, 4)
void gemm_mfma(const u16* __restrict__ A0, const u16* __restrict__ A1,
               const u16* __restrict__ W, const float* __restrict__ bias,
               void* __restrict__ C0, void* __restrict__ C1,
               u16* __restrict__ VTout)
{
  __shared__ u16 As[2][128 * 64];
  __shared__ u16 Bs[2][128 * 64];

  int m_t, n_t, z_;
  if (SWZ) {
    const int id = blockIdx.x;  // grid dim3(768, 2)
    z_ = blockIdx.y;
    if (z_ == 0) {
      const int xcd = id & 7, slot = id >> 3;          // 96 slots
      m_t = (xcd >> 2) * 16 + (slot & 15);             // 2 x 16 m-tiles
      n_t = (xcd & 3) * 6 + (slot >> 4);               // 4 x 6 col-tiles
    } else {
      if (id >= 576) return;                           // 32m x 18col only
      const int xcd = id & 7, slot = id >> 3;          // 72 slots
      m_t = (xcd >> 1) * 8 + (slot & 7);               // 4 x 8 m-tiles
      n_t = (xcd & 1) * 9 + (slot >> 3);               // 2 x 9 col-tiles
    }
  } else {
    m_t = blockIdx.y; n_t = blockIdx.x; z_ = blockIdx.z;
  }
  const int m0 = m_t * 128, n0 = n_t * 128;
  if (!SWZ && z_ && n0 >= NZ1) return;
  const u16* A = z_ ? A1 : A0;
  void* C = z_ ? C1 : C0;
  const int t = threadIdx.x, w = t >> 6, lane = t & 63;
  const int c = lane & 15, qq = lane >> 4;
  const int mq = (w >> 2) * 64, nq = (w & 3) * 32;  // wave -> 64x32 sub-tile

  const int lr = lane >> 3;
  const int lchunk = (lane & 7) ^ lr;
  int arow[2], brow[2];
#pragma unroll
  for (int i = 0; i < 2; i++) {
    const int r = (w * 2 + i) * 8 + lr;   // 16 segs x 8 rows = 128 rows
    arow[i] = (m0 + r) * 768 + lchunk * 8;
    brow[i] = (n0 + r) * 768 + lchunk * 8;
  }

  // prologue: stage K-step 0 into buffer 0
#pragma unroll
  for (int i = 0; i < 2; i++) {
    load_lds16(A + arow[i], As[0] + (w * 2 + i) * 512);
    load_lds16(W + brow[i], Bs[0] + (w * 2 + i) * 512);
  }
  __syncthreads();

  f32x4 acc[4][2] = {};
  for (int kt = 0; kt < 12; ++kt) {
    const int cur = kt & 1;
    // issue next K-step staging before compute (drain lands after compute)
    if (kt < 11) {
      const int k1 = (kt + 1) * 64;
#pragma unroll
      for (int i = 0; i < 2; i++) {
        load_lds16(A + arow[i] + k1, As[cur ^ 1] + (w * 2 + i) * 512);
        load_lds16(W + brow[i] + k1, Bs[cur ^ 1] + (w * 2 + i) * 512);
      }
    }
#pragma unroll
    for (int s = 0; s < 2; s++) {
      const int swz = ((s * 4 + qq) ^ (c & 7)) * 8;
      short8 af[4], bf[2];
#pragma unroll
      for (int i = 0; i < 4; i++)
        af[i] = *(const short8*)&As[cur][(mq + i * 16 + c) * 64 + swz];
#pragma unroll
      for (int j = 0; j < 2; j++)
        bf[j] = *(const short8*)&Bs[cur][(nq + j * 16 + c) * 64 + swz];
#pragma unroll
      for (int i = 0; i < 4; i++)
#pragma unroll
        for (int j = 0; j < 2; j++)
          acc[i][j] = __builtin_amdgcn_mfma_f32_16x16x32_bf16(af[i], bf[j], acc[i][j], 0, 0, 0);
    }
    __syncthreads();  // reads of buf[cur] done; buf[cur^1] staged
  }

  if (VSPLIT && z_ == 0 && n0 >= 2304) {
    // v-block epilogue: transposed + key-permuted scatter into VT
#pragma unroll
    for (int i = 0; i < 4; i++)
#pragma unroll
      for (int r = 0; r < 4; r++) {
        const int m = m0 + mq + i * 16 + qq * 4 + r;       // b*1024 + key
        const int b_ = m >> 10, key = m & 1023;
        const int kt = key >> 5, kk = key & 31;
        const int mcol = kt * 32 + ((kk >> 2) & 3) * 8 + ((kk >> 4) & 1) * 4 + (kk & 3);
#pragma unroll
        for (int j = 0; j < 2; j++) {
          const int pl = n0 - 2304 + nq + c + j * 16;      // h*64 + d
          const int h_ = pl >> 6, d_ = pl & 63;
          VTout[(size_t)((b_ * HH + h_) * 64 + d_) * 1024 + mcol] = f2bf(acc[i][j][r]);
        }
      }
    return;
  }

  float bj[2] = {0.f, 0.f};
  if (BIAS) {
#pragma unroll
    for (int j = 0; j < 2; j++) bj[j] = bias[n0 + nq + c + j * 16];
  }
#pragma unroll
  for (int i = 0; i < 4; i++)
#pragma unroll
    for (int r = 0; r < 4; r++) {
      const size_t row = (size_t)(m0 + mq + i * 16 + qq * 4 + r) * NP + n0 + nq + c;
      if (BF16OUT) {
#pragma unroll
        for (int j = 0; j < 2; j++)
          ((u16*)C)[row + j * 16] = f2bf(acc[i][j][r]);
      } else {
#pragma unroll
        for (int j = 0; j < 2; j++)
          ((float*)C)[row + j * 16] = acc[i][j][r] + bj[j];
      }
    }
}

// MFMA attention v13 (unchanged, verified) — concat-P via key-permuted VT,
// K/VT double-buffer, 36864 B LDS pad capping 4 blocks/CU for per-XCD L2 fit
// (LOAD-BEARING: v11 showed >4 blocks/CU overflows 4MB L2 -> WRITE 63 MB),
// T5 setprio around the MFMA cluster.
__global__ __launch_bounds__(256, 4)
void attn_pair_mfma(const u16* __restrict__ qkvx, const u16* __restrict__ qkvy,
                    const u16* __restrict__ VT,
                    u16* __restrict__ sum_x, u16* __restrict__ sum_y)
{
  // 36864 B (occupancy cap). u16 layout: K0 [0,4096) K1 [4096,8192)
  // V0 [8192,12288) V1 [12288,16384); rest pad. Epilogue: Of 64x68 f32 alias.
  __shared__ __align__(16) u16 smem[18432];
  float (*Of)[68] = (float(*)[68])smem;

  // XCD-aware decode (perf heuristic only)
  const int blk = blockIdx.x;                // 1536 blocks
  const int xcd = blk & 7, slot = blk >> 3;  // 192 slots
  const int bh = (slot >> 5) * 8 + xcd;      // 6 groups x 8 = 48
  const int inner = slot & 31;
  const int qt = inner >> 1, pair = inner & 1;
  const int b = bh / HH, head = bh % HH;
  const u16* q1 = pair ? qkvy : qkvx;  // self q   (j=1, +scale folded)
  const u16* q2 = pair ? qkvx : qkvy;  // cross qo (j=0, -scale folded)
  const u16* ks = pair ? qkvy : qkvx;  // k (j=2)
  u16* outp = pair ? sum_y : sum_x;

  const int t = threadIdx.x, w = t >> 6, lane = t & 63;
  const int c = lane & 15, qq = lane >> 4;

  // Q B-frags (lane n=c holds q-row c of the wave's 16-row tile): 2 sets
  short8 Qf[2][2];
  {
    const int qrow = qt * 64 + w * 16 + c;
    const u16* qs = q1 + (size_t)(b * NN + qrow) * 3072 + CC + head * HD + qq * 8;
    const u16* qc = q2 + (size_t)(b * NN + qrow) * 3072 + head * HD + qq * 8;
    Qf[0][0] = *(const short8*)qs;
    Qf[0][1] = *(const short8*)(qs + 32);
    Qf[1][0] = *(const short8*)qc;
    Qf[1][1] = *(const short8*)(qc + 32);
  }

  const u16* kbase = ks + (size_t)(b * NN) * 3072 + 2 * CC + head * HD;
  const u16* vtb = VT + (size_t)(bh * 64) * 1024;

  const int lr = lane >> 3;
  const int sc8 = ((lane & 7) ^ lr) * 8;

  short8 ones;
#pragma unroll
  for (int i = 0; i < 8; i++) ones[i] = (short)0x3F80;  // bf16 1.0

  f32x4 O[2][4] = {};  // [set][t4]
  f32x4 L[2] = {};

  const int cx = c & 7;
  const int koff0 = (qq ^ cx) * 8;          // K/VT buffers: XOR staging layout
  const int koff1 = ((4 + qq) ^ cx) * 8;

  // prologue: stage tile 0 into buffer 0
#pragma unroll
  for (int i = 0; i < 2; i++) {
    const int r = (2 * w + i) * 8 + lr;
    load_lds16(kbase + (size_t)r * 3072 + sc8, smem + (2 * w + i) * 512);
    load_lds16(vtb + (size_t)r * 1024 + sc8, smem + 8192 + (2 * w + i) * 512);
  }
  __syncthreads();  // vmcnt(0) drain: tile 0 staged

  for (int c16 = 0; c16 < 16; ++c16) {
    const int cur = c16 & 1;
    const u16* Kb = smem + cur * 4096;
    const u16* Vb = smem + 8192 + cur * 4096;

    // issue next-tile staging before compute (latency hides under MFMA/exp2;
    // the end-of-iter barrier's implicit vmcnt(0) lands after compute)
    if (c16 < 15) {
      u16* Kn = smem + (cur ^ 1) * 4096;
      u16* Vn = smem + 8192 + (cur ^ 1) * 4096;
#pragma unroll
      for (int i = 0; i < 2; i++) {
        const int r = (2 * w + i) * 8 + lr;
        load_lds16(kbase + (size_t)((c16 + 1) * 64 + r) * 3072 + sc8,
                   Kn + (2 * w + i) * 512);
        load_lds16(vtb + (size_t)r * 1024 + (c16 + 1) * 64 + sc8,
                   Vn + (2 * w + i) * 512);
      }
    }

    __builtin_amdgcn_s_setprio(1);  // T5: favor this wave through the MFMA cluster

    // S^T per t4-tile for both sets; exp2 + pack kept in registers:
    // pk[s][t4][0] = keys (16t4+4qq+0, +1), pk[s][t4][1] = (+2, +3) as bf16x2
    unsigned pk[2][4][2];
#pragma unroll
    for (int t4 = 0; t4 < 4; t4++) {
      const u16* kr = Kb + (16 * t4 + c) * 64;
      short8 k0 = *(const short8*)(kr + koff0);
      short8 k1 = *(const short8*)(kr + koff1);
#pragma unroll
      for (int s = 0; s < 2; s++) {
        f32x4 z = {0.f, 0.f, 0.f, 0.f};
        z = __builtin_amdgcn_mfma_f32_16x16x32_bf16(k0, Qf[s][0], z, 0, 0, 0);
        z = __builtin_amdgcn_mfma_f32_16x16x32_bf16(k1, Qf[s][1], z, 0, 0, 0);
        unsigned int u0 = __float_as_uint(__ocml_native_exp2_f32(z[0]));
        unsigned int u1 = __float_as_uint(__ocml_native_exp2_f32(z[1]));
        unsigned int u2 = __float_as_uint(__ocml_native_exp2_f32(z[2]));
        unsigned int u3 = __float_as_uint(__ocml_native_exp2_f32(z[3]));
        pk[s][t4][0] = __builtin_amdgcn_perm(u1, u0, 0x07060302u);  // hi(u1)|hi(u0)
        pk[s][t4][1] = __builtin_amdgcn_perm(u3, u2, 0x07060302u);
      }
    }

    // PV A-frags by pure concatenation (k-slot j -> key 4qq+j / 16+4qq+j-4,
    // matched by the fused-epilogue VT column permutation). L via ones-MFMA.
    short8 pa[2][2];
#pragma unroll
    for (int s = 0; s < 2; s++) {
      union { unsigned u[4]; short8 s8; } f0, f1;
      f0.u[0] = pk[s][0][0]; f0.u[1] = pk[s][0][1];
      f0.u[2] = pk[s][1][0]; f0.u[3] = pk[s][1][1];
      f1.u[0] = pk[s][2][0]; f1.u[1] = pk[s][2][1];
      f1.u[2] = pk[s][3][0]; f1.u[3] = pk[s][3][1];
      pa[s][0] = f0.s8;
      pa[s][1] = f1.s8;
      L[s] = __builtin_amdgcn_mfma_f32_16x16x32_bf16(pa[s][0], ones, L[s], 0, 0, 0);
      L[s] = __builtin_amdgcn_mfma_f32_16x16x32_bf16(pa[s][1], ones, L[s], 0, 0, 0);
    }

    // PV
#pragma unroll
    for (int t4 = 0; t4 < 4; t4++) {
      const u16* vr = Vb + (16 * t4 + c) * 64;
      short8 v0 = *(const short8*)(vr + koff0);
      short8 v1 = *(const short8*)(vr + koff1);
#pragma unroll
      for (int s = 0; s < 2; s++) {
        O[s][t4] = __builtin_amdgcn_mfma_f32_16x16x32_bf16(pa[s][0], v0, O[s][t4], 0, 0, 0);
        O[s][t4] = __builtin_amdgcn_mfma_f32_16x16x32_bf16(pa[s][1], v1, O[s][t4], 0, 0, 0);
      }
    }

    __builtin_amdgcn_s_setprio(0);

    __syncthreads();  // all reads of buf[cur] done; buf[cur^1] staged
  }

  // loop-end barrier already synced all waves -> realias K/V region as Of
  float is[4], ic[4];
#pragma unroll
  for (int r = 0; r < 4; r++) {
    is[r] = 1.0f / L[0][r];
    ic[r] = 1.0f / L[1][r];
  }
#pragma unroll
  for (int t4 = 0; t4 < 4; t4++)
#pragma unroll
    for (int r = 0; r < 4; r++)
      Of[w * 16 + 4 * qq + r][16 * t4 + c] =
          O[0][t4][r] * is[r] + O[1][t4][r] * ic[r];
  __syncthreads();
  // out[b, qt*64+row, head*64+d] (bf16, coalesced)
#pragma unroll
  for (int p = 0; p < 4; p++) {
    const int idx = p * 256 + t;
    const int row = idx >> 4, c4 = (idx & 15) * 4;
    float4 v = *(const float4*)&Of[row][c4];
    ushort4 u = {f2bf(v.x), f2bf(v.y), f2bf(v.z), f2bf(v.w)};
    *(ushort4*)(outp + (size_t)(b * NN + qt * 64 + row) * CC + head * HD + c4) = u;
  }
}

extern "C" void kernel_launch(void* const* d_in, const int* in_sizes, int n_in,
                              void* d_out, int out_size, void* d_ws, size_t ws_size,
                              hipStream_t stream)
{
  const float* x      = (const float*)d_in[0];
  const float* y      = (const float*)d_in[1];
  const float* w_qkv  = (const float*)d_in[2];
  const float* w_proj = (const float*)d_in[3];
  const float* b_proj = (const float*)d_in[4];

  // ws layout (75.1 MB used):
  //   qkv_x 25.2 | qkv_y 25.2 | sum_x 6.3 (alias x_bf) | sum_y 6.3 (alias y_bf)
  //   | wq_bf 4.7 | wp_bf 1.2 | VT 6.3
  u16* qkv_x = (u16*)d_ws;
  u16* qkv_y = qkv_x + (size_t)4096 * 3072;
  u16* rest = qkv_y + (size_t)4096 * 3072;
  u16* sum_x = rest;
  u16* sum_y = sum_x + (size_t)4096 * 768;
  u16* x_bf  = rest;                       // aliases sum_x (dead after QKV)
  u16* y_bf  = x_bf + (size_t)4096 * 768;  // aliases sum_y
  u16* wq_bf = y_bf + (size_t)4096 * 768;
  u16* wp_bf = wq_bf + (size_t)3072 * 768;
  u16* VT    = wp_bf + (size_t)768 * 768;
  float* out_x = (float*)d_out;
  float* out_y = out_x + (size_t)4096 * 768;

  // 0) fp32 -> bf16 (w_qkv query rows pre-scaled by ±0.125·log2e)
  cvt_bf16<<<dim3(1536, 4), 256, 0, stream>>>(x, y, w_qkv, w_proj,
                                              x_bf, y_bf, wq_bf, wp_bf);

  // 1) QKV via MFMA: qkv_{x,y} = {x,y}_bf @ wq_bf^T (bf16 out).
  //    XCD-chunked swizzled grid (768 x 2); y's dead v-block skipped by the
  //    z=1 decode (18 col-tiles); x's v-block written DIRECTLY to VT
  //    (transposed + key-permuted) — vtrans fused. Double-buffered staging.
  gemm_mfma<3072, true, false, 2304, true, true><<<dim3(768, 2), 512, 0, stream>>>(
      x_bf, y_bf, wq_bf, nullptr, qkv_x, qkv_y, VT);

  // 2) paired MFMA attention -> sum_x, sum_y (bf16), XCD-swizzled 1-D grid
  attn_pair_mfma<<<dim3(1536), 256, 0, stream>>>(qkv_x, qkv_y, VT, sum_x, sum_y);

  // 3) out = sum @ wp_bf^T + b_proj (f32, MFMA), dbuf, unswizzled 3-D grid
  gemm_mfma<768, false, true, 768, false, false><<<dim3(6, 32, 2), 512, 0, stream>>>(
      sum_x, sum_y, wp_bf, b_proj, out_x, out_y, nullptr);
}

// Round 10
// 210.142 us; speedup vs baseline: 1.0095x; 1.0095x over previous
//
#include <hip/hip_runtime.h>
#include <hip/hip_bf16.h>
#include <stdint.h>

// Problem: B=4, N=1024, C=768, H=12, hd=64.
// out_x = (attn(qx,kx,vx,+) + attn(qyo,kx,vx,-)) @ Wp^T + bp
// out_y = (attn(qy,ky,vx,+) + attn(qxo,ky,vx,-)) @ Wp^T + bp   (vy = vx!)
// qkv[b,n, j*768 + h*64 + d], j in {0:qo, 1:q, 2:k, 3:v}
// NOTE: w_qkv rows j=0 are pre-scaled by -0.125*log2(e), j=1 by +0.125*log2(e)
// in cvt_bf16, so attention scores emerge in the log2 domain with sign folded:
// softmax is exp2(s) directly for BOTH self and cross attends.

#define BB 4
#define NN 1024
#define CC 768
#define HH 12
#define HD 64

typedef unsigned short u16;
typedef short short8 __attribute__((ext_vector_type(8)));
typedef float f32x4 __attribute__((ext_vector_type(4)));

extern "C" __device__ float __ocml_native_exp2_f32(float);

__device__ __forceinline__ u16 f2bf(float f) {
  unsigned int u = __float_as_uint(f);
  return (u16)((u + 0x7fffu + ((u >> 16) & 1u)) >> 16);
}

__device__ __forceinline__ void load_lds16(const u16* g, u16* l) {
  __builtin_amdgcn_global_load_lds((__attribute__((address_space(1))) const void*)g,
                                   (__attribute__((address_space(3))) void*)l, 16, 0, 0);
}

// fp32 -> bf16 conversion: seg 0=x, 1=y, 2=w_qkv (query rows pre-scaled), 3=w_proj
__global__ __launch_bounds__(256)
void cvt_bf16(const float* __restrict__ x, const float* __restrict__ y,
              const float* __restrict__ wq, const float* __restrict__ wp,
              u16* __restrict__ xb, u16* __restrict__ yb,
              u16* __restrict__ wqb, u16* __restrict__ wpb)
{
  const int seg = blockIdx.y;
  const float* src = seg == 0 ? x : (seg == 1 ? y : (seg == 2 ? wq : wp));
  u16* dst = seg == 0 ? xb : (seg == 1 ? yb : (seg == 2 ? wqb : wpb));
  const int n = (seg == 3) ? 768 * 768 : ((seg == 2) ? 3072 * 768 : 4096 * 768);
  const int i = (blockIdx.x * 256 + threadIdx.x) * 8;
  if (i >= n) return;
  float sc = 1.0f;
  if (seg == 2) {
    const int row = i / 768;  // output feature p; j = p/768
    sc = (row < 768) ? -0.18033688f : (row < 1536 ? 0.18033688f : 1.0f);
  }
  float4 a = *(const float4*)(src + i);
  float4 b = *(const float4*)(src + i + 4);
  ushort4 u0 = {f2bf(a.x * sc), f2bf(a.y * sc), f2bf(a.z * sc), f2bf(a.w * sc)};
  ushort4 u1 = {f2bf(b.x * sc), f2bf(b.y * sc), f2bf(b.z * sc), f2bf(b.w * sc)};
  *(ushort4*)(dst + i) = u0;
  *(ushort4*)(dst + i + 4) = u1;
}

// MFMA GEMM v16: C[m,p] = A[m,:] . W[p,:] (+bias). 128x128 tile, BK=64,
// 8 waves (512 thr), wave -> 64x32 sub-tile (acc[4][2]=32 AGPRs; v14
// occupancy fix) + 2-phase double-buffered staging (ONE barrier per K-step,
// 12 vs 24; drain covered by the 16 MFMAs + fragment reads). LDS 64 KB x2buf;
// residency unchanged (reg-capped 2 blocks/CU, 128 KB <= 160 KB).
// v15's XCD-chunk swizzle REVERTED (isolation): the two concurrent z-planes
// gave each XCD a combined 7.7 MB chunk footprint ~2x the 4 MB L2 — the
// chunking concentrated misses; total regressed 203.9 -> 212.1.
// NZ1: column limit for blockIdx.z==1 (qkv_y's v-block j=3 is never read).
// VSPLIT: z==0, n0 in [2304,3072): epilogue writes VT directly (transposed +
// key-permuted, v11-verified) instead of C.
template<int NP, bool BF16OUT, bool BIAS, int NZ1, bool VSPLIT>
__global__ __launch_bounds__(512, 4)
void gemm_mfma(const u16* __restrict__ A0, const u16* __restrict__ A1,
               const u16* __restrict__ W, const float* __restrict__ bias,
               void* __restrict__ C0, void* __restrict__ C1,
               u16* __restrict__ VTout)
{
  __shared__ u16 As[2][128 * 64];
  __shared__ u16 Bs[2][128 * 64];
  const int m0 = blockIdx.y * 128, n0 = blockIdx.x * 128;
  if (blockIdx.z && n0 >= NZ1) return;
  const u16* A = blockIdx.z ? A1 : A0;
  void* C = blockIdx.z ? C1 : C0;
  const int t = threadIdx.x, w = t >> 6, lane = t & 63;
  const int c = lane & 15, qq = lane >> 4;
  const int mq = (w >> 2) * 64, nq = (w & 3) * 32;  // wave -> 64x32 sub-tile

  const int lr = lane >> 3;
  const int lchunk = (lane & 7) ^ lr;
  int arow[2], brow[2];
#pragma unroll
  for (int i = 0; i < 2; i++) {
    const int r = (w * 2 + i) * 8 + lr;   // 16 segs x 8 rows = 128 rows
    arow[i] = (m0 + r) * 768 + lchunk * 8;
    brow[i] = (n0 + r) * 768 + lchunk * 8;
  }

  // prologue: stage K-step 0 into buffer 0
#pragma unroll
  for (int i = 0; i < 2; i++) {
    load_lds16(A + arow[i], As[0] + (w * 2 + i) * 512);
    load_lds16(W + brow[i], Bs[0] + (w * 2 + i) * 512);
  }
  __syncthreads();

  f32x4 acc[4][2] = {};
  for (int kt = 0; kt < 12; ++kt) {
    const int cur = kt & 1;
    // issue next K-step staging before compute (drain lands after compute;
    // end-of-prev-step barrier guaranteed buf[cur^1] reads are done)
    if (kt < 11) {
      const int k1 = (kt + 1) * 64;
#pragma unroll
      for (int i = 0; i < 2; i++) {
        load_lds16(A + arow[i] + k1, As[cur ^ 1] + (w * 2 + i) * 512);
        load_lds16(W + brow[i] + k1, Bs[cur ^ 1] + (w * 2 + i) * 512);
      }
    }
#pragma unroll
    for (int s = 0; s < 2; s++) {
      const int swz = ((s * 4 + qq) ^ (c & 7)) * 8;
      short8 af[4], bf[2];
#pragma unroll
      for (int i = 0; i < 4; i++)
        af[i] = *(const short8*)&As[cur][(mq + i * 16 + c) * 64 + swz];
#pragma unroll
      for (int j = 0; j < 2; j++)
        bf[j] = *(const short8*)&Bs[cur][(nq + j * 16 + c) * 64 + swz];
#pragma unroll
      for (int i = 0; i < 4; i++)
#pragma unroll
        for (int j = 0; j < 2; j++)
          acc[i][j] = __builtin_amdgcn_mfma_f32_16x16x32_bf16(af[i], bf[j], acc[i][j], 0, 0, 0);
    }
    __syncthreads();  // reads of buf[cur] done; buf[cur^1] staged
  }

  if (VSPLIT && blockIdx.z == 0 && n0 >= 2304) {
    // v-block epilogue: transposed + key-permuted scatter into VT
#pragma unroll
    for (int i = 0; i < 4; i++)
#pragma unroll
      for (int r = 0; r < 4; r++) {
        const int m = m0 + mq + i * 16 + qq * 4 + r;       // b*1024 + key
        const int b_ = m >> 10, key = m & 1023;
        const int kt = key >> 5, kk = key & 31;
        const int mcol = kt * 32 + ((kk >> 2) & 3) * 8 + ((kk >> 4) & 1) * 4 + (kk & 3);
#pragma unroll
        for (int j = 0; j < 2; j++) {
          const int pl = n0 - 2304 + nq + c + j * 16;      // h*64 + d
          const int h_ = pl >> 6, d_ = pl & 63;
          VTout[(size_t)((b_ * HH + h_) * 64 + d_) * 1024 + mcol] = f2bf(acc[i][j][r]);
        }
      }
    return;
  }

  float bj[2] = {0.f, 0.f};
  if (BIAS) {
#pragma unroll
    for (int j = 0; j < 2; j++) bj[j] = bias[n0 + nq + c + j * 16];
  }
#pragma unroll
  for (int i = 0; i < 4; i++)
#pragma unroll
    for (int r = 0; r < 4; r++) {
      const size_t row = (size_t)(m0 + mq + i * 16 + qq * 4 + r) * NP + n0 + nq + c;
      if (BF16OUT) {
#pragma unroll
        for (int j = 0; j < 2; j++)
          ((u16*)C)[row + j * 16] = f2bf(acc[i][j][r]);
      } else {
#pragma unroll
        for (int j = 0; j < 2; j++)
          ((float*)C)[row + j * 16] = acc[i][j][r] + bj[j];
      }
    }
}

// MFMA attention v13 (unchanged, verified) — concat-P via key-permuted VT,
// K/VT double-buffer, 36864 B LDS pad capping 4 blocks/CU for per-XCD L2 fit
// (LOAD-BEARING: v11 showed >4 blocks/CU overflows 4MB L2 -> WRITE 63 MB),
// T5 setprio around the MFMA cluster.
__global__ __launch_bounds__(256, 4)
void attn_pair_mfma(const u16* __restrict__ qkvx, const u16* __restrict__ qkvy,
                    const u16* __restrict__ VT,
                    u16* __restrict__ sum_x, u16* __restrict__ sum_y)
{
  // 36864 B (occupancy cap). u16 layout: K0 [0,4096) K1 [4096,8192)
  // V0 [8192,12288) V1 [12288,16384); rest pad. Epilogue: Of 64x68 f32 alias.
  __shared__ __align__(16) u16 smem[18432];
  float (*Of)[68] = (float(*)[68])smem;

  // XCD-aware decode (perf heuristic only)
  const int blk = blockIdx.x;                // 1536 blocks
  const int xcd = blk & 7, slot = blk >> 3;  // 192 slots
  const int bh = (slot >> 5) * 8 + xcd;      // 6 groups x 8 = 48
  const int inner = slot & 31;
  const int qt = inner >> 1, pair = inner & 1;
  const int b = bh / HH, head = bh % HH;
  const u16* q1 = pair ? qkvy : qkvx;  // self q   (j=1, +scale folded)
  const u16* q2 = pair ? qkvx : qkvy;  // cross qo (j=0, -scale folded)
  const u16* ks = pair ? qkvy : qkvx;  // k (j=2)
  u16* outp = pair ? sum_y : sum_x;

  const int t = threadIdx.x, w = t >> 6, lane = t & 63;
  const int c = lane & 15, qq = lane >> 4;

  // Q B-frags (lane n=c holds q-row c of the wave's 16-row tile): 2 sets
  short8 Qf[2][2];
  {
    const int qrow = qt * 64 + w * 16 + c;
    const u16* qs = q1 + (size_t)(b * NN + qrow) * 3072 + CC + head * HD + qq * 8;
    const u16* qc = q2 + (size_t)(b * NN + qrow) * 3072 + head * HD + qq * 8;
    Qf[0][0] = *(const short8*)qs;
    Qf[0][1] = *(const short8*)(qs + 32);
    Qf[1][0] = *(const short8*)qc;
    Qf[1][1] = *(const short8*)(qc + 32);
  }

  const u16* kbase = ks + (size_t)(b * NN) * 3072 + 2 * CC + head * HD;
  const u16* vtb = VT + (size_t)(bh * 64) * 1024;

  const int lr = lane >> 3;
  const int sc8 = ((lane & 7) ^ lr) * 8;

  short8 ones;
#pragma unroll
  for (int i = 0; i < 8; i++) ones[i] = (short)0x3F80;  // bf16 1.0

  f32x4 O[2][4] = {};  // [set][t4]
  f32x4 L[2] = {};

  const int cx = c & 7;
  const int koff0 = (qq ^ cx) * 8;          // K/VT buffers: XOR staging layout
  const int koff1 = ((4 + qq) ^ cx) * 8;

  // prologue: stage tile 0 into buffer 0
#pragma unroll
  for (int i = 0; i < 2; i++) {
    const int r = (2 * w + i) * 8 + lr;
    load_lds16(kbase + (size_t)r * 3072 + sc8, smem + (2 * w + i) * 512);
    load_lds16(vtb + (size_t)r * 1024 + sc8, smem + 8192 + (2 * w + i) * 512);
  }
  __syncthreads();  // vmcnt(0) drain: tile 0 staged

  for (int c16 = 0; c16 < 16; ++c16) {
    const int cur = c16 & 1;
    const u16* Kb = smem + cur * 4096;
    const u16* Vb = smem + 8192 + cur * 4096;

    // issue next-tile staging before compute (latency hides under MFMA/exp2;
    // the end-of-iter barrier's implicit vmcnt(0) lands after compute)
    if (c16 < 15) {
      u16* Kn = smem + (cur ^ 1) * 4096;
      u16* Vn = smem + 8192 + (cur ^ 1) * 4096;
#pragma unroll
      for (int i = 0; i < 2; i++) {
        const int r = (2 * w + i) * 8 + lr;
        load_lds16(kbase + (size_t)((c16 + 1) * 64 + r) * 3072 + sc8,
                   Kn + (2 * w + i) * 512);
        load_lds16(vtb + (size_t)r * 1024 + (c16 + 1) * 64 + sc8,
                   Vn + (2 * w + i) * 512);
      }
    }

    __builtin_amdgcn_s_setprio(1);  // T5: favor this wave through the MFMA cluster

    // S^T per t4-tile for both sets; exp2 + pack kept in registers:
    // pk[s][t4][0] = keys (16t4+4qq+0, +1), pk[s][t4][1] = (+2, +3) as bf16x2
    unsigned pk[2][4][2];
#pragma unroll
    for (int t4 = 0; t4 < 4; t4++) {
      const u16* kr = Kb + (16 * t4 + c) * 64;
      short8 k0 = *(const short8*)(kr + koff0);
      short8 k1 = *(const short8*)(kr + koff1);
#pragma unroll
      for (int s = 0; s < 2; s++) {
        f32x4 z = {0.f, 0.f, 0.f, 0.f};
        z = __builtin_amdgcn_mfma_f32_16x16x32_bf16(k0, Qf[s][0], z, 0, 0, 0);
        z = __builtin_amdgcn_mfma_f32_16x16x32_bf16(k1, Qf[s][1], z, 0, 0, 0);
        unsigned int u0 = __float_as_uint(__ocml_native_exp2_f32(z[0]));
        unsigned int u1 = __float_as_uint(__ocml_native_exp2_f32(z[1]));
        unsigned int u2 = __float_as_uint(__ocml_native_exp2_f32(z[2]));
        unsigned int u3 = __float_as_uint(__ocml_native_exp2_f32(z[3]));
        pk[s][t4][0] = __builtin_amdgcn_perm(u1, u0, 0x07060302u);  // hi(u1)|hi(u0)
        pk[s][t4][1] = __builtin_amdgcn_perm(u3, u2, 0x07060302u);
      }
    }

    // PV A-frags by pure concatenation (k-slot j -> key 4qq+j / 16+4qq+j-4,
    // matched by the fused-epilogue VT column permutation). L via ones-MFMA.
    short8 pa[2][2];
#pragma unroll
    for (int s = 0; s < 2; s++) {
      union { unsigned u[4]; short8 s8; } f0, f1;
      f0.u[0] = pk[s][0][0]; f0.u[1] = pk[s][0][1];
      f0.u[2] = pk[s][1][0]; f0.u[3] = pk[s][1][1];
      f1.u[0] = pk[s][2][0]; f1.u[1] = pk[s][2][1];
      f1.u[2] = pk[s][3][0]; f1.u[3] = pk[s][3][1];
      pa[s][0] = f0.s8;
      pa[s][1] = f1.s8;
      L[s] = __builtin_amdgcn_mfma_f32_16x16x32_bf16(pa[s][0], ones, L[s], 0, 0, 0);
      L[s] = __builtin_amdgcn_mfma_f32_16x16x32_bf16(pa[s][1], ones, L[s], 0, 0, 0);
    }

    // PV
#pragma unroll
    for (int t4 = 0; t4 < 4; t4++) {
      const u16* vr = Vb + (16 * t4 + c) * 64;
      short8 v0 = *(const short8*)(vr + koff0);
      short8 v1 = *(const short8*)(vr + koff1);
#pragma unroll
      for (int s = 0; s < 2; s++) {
        O[s][t4] = __builtin_amdgcn_mfma_f32_16x16x32_bf16(pa[s][0], v0, O[s][t4], 0, 0, 0);
        O[s][t4] = __builtin_amdgcn_mfma_f32_16x16x32_bf16(pa[s][1], v1, O[s][t4], 0, 0, 0);
      }
    }

    __builtin_amdgcn_s_setprio(0);

    __syncthreads();  // all reads of buf[cur] done; buf[cur^1] staged
  }

  // loop-end barrier already synced all waves -> realias K/V region as Of
  float is[4], ic[4];
#pragma unroll
  for (int r = 0; r < 4; r++) {
    is[r] = 1.0f / L[0][r];
    ic[r] = 1.0f / L[1][r];
  }
#pragma unroll
  for (int t4 = 0; t4 < 4; t4++)
#pragma unroll
    for (int r = 0; r < 4; r++)
      Of[w * 16 + 4 * qq + r][16 * t4 + c] =
          O[0][t4][r] * is[r] + O[1][t4][r] * ic[r];
  __syncthreads();
  // out[b, qt*64+row, head*64+d] (bf16, coalesced)
#pragma unroll
  for (int p = 0; p < 4; p++) {
    const int idx = p * 256 + t;
    const int row = idx >> 4, c4 = (idx & 15) * 4;
    float4 v = *(const float4*)&Of[row][c4];
    ushort4 u = {f2bf(v.x), f2bf(v.y), f2bf(v.z), f2bf(v.w)};
    *(ushort4*)(outp + (size_t)(b * NN + qt * 64 + row) * CC + head * HD + c4) = u;
  }
}

extern "C" void kernel_launch(void* const* d_in, const int* in_sizes, int n_in,
                              void* d_out, int out_size, void* d_ws, size_t ws_size,
                              hipStream_t stream)
{
  const float* x      = (const float*)d_in[0];
  const float* y      = (const float*)d_in[1];
  const float* w_qkv  = (const float*)d_in[2];
  const float* w_proj = (const float*)d_in[3];
  const float* b_proj = (const float*)d_in[4];

  // ws layout (75.1 MB used):
  //   qkv_x 25.2 | qkv_y 25.2 | sum_x 6.3 (alias x_bf) | sum_y 6.3 (alias y_bf)
  //   | wq_bf 4.7 | wp_bf 1.2 | VT 6.3
  u16* qkv_x = (u16*)d_ws;
  u16* qkv_y = qkv_x + (size_t)4096 * 3072;
  u16* rest = qkv_y + (size_t)4096 * 3072;
  u16* sum_x = rest;
  u16* sum_y = sum_x + (size_t)4096 * 768;
  u16* x_bf  = rest;                       // aliases sum_x (dead after QKV)
  u16* y_bf  = x_bf + (size_t)4096 * 768;  // aliases sum_y
  u16* wq_bf = y_bf + (size_t)4096 * 768;
  u16* wp_bf = wq_bf + (size_t)3072 * 768;
  u16* VT    = wp_bf + (size_t)768 * 768;
  float* out_x = (float*)d_out;
  float* out_y = out_x + (size_t)4096 * 768;

  // 0) fp32 -> bf16 (w_qkv query rows pre-scaled by ±0.125·log2e)
  cvt_bf16<<<dim3(1536, 4), 256, 0, stream>>>(x, y, w_qkv, w_proj,
                                              x_bf, y_bf, wq_bf, wp_bf);

  // 1) QKV via MFMA: qkv_{x,y} = {x,y}_bf @ wq_bf^T (bf16 out).
  //    y skips its dead v-block (n0 >= 2304); x's v-block is written DIRECTLY
  //    to VT (transposed + key-permuted) — vtrans fused. Dbuf staging.
  gemm_mfma<3072, true, false, 2304, true><<<dim3(24, 32, 2), 512, 0, stream>>>(
      x_bf, y_bf, wq_bf, nullptr, qkv_x, qkv_y, VT);

  // 2) paired MFMA attention -> sum_x, sum_y (bf16), XCD-swizzled 1-D grid
  attn_pair_mfma<<<dim3(1536), 256, 0, stream>>>(qkv_x, qkv_y, VT, sum_x, sum_y);

  // 3) out = sum @ wp_bf^T + b_proj (f32, MFMA), dbuf staging
  gemm_mfma<768, false, true, 768, false><<<dim3(6, 32, 2), 512, 0, stream>>>(
      sum_x, sum_y, wp_bf, b_proj, out_x, out_y, nullptr);
}

// Round 11
// 197.228 us; speedup vs baseline: 1.0756x; 1.0655x over previous
//
#include <hip/hip_runtime.h>
#include <hip/hip_bf16.h>
#include <stdint.h>

// Problem: B=4, N=1024, C=768, H=12, hd=64.
// out_x = (attn(qx,kx,vx,+) + attn(qyo,kx,vx,-)) @ Wp^T + bp
// out_y = (attn(qy,ky,vx,+) + attn(qxo,ky,vx,-)) @ Wp^T + bp   (vy = vx!)
// qkv[b,n, j*768 + h*64 + d], j in {0:qo, 1:q, 2:k, 3:v}
// NOTE: w_qkv rows j=0 are pre-scaled by -0.125*log2(e), j=1 by +0.125*log2(e)
// in cvt_bf16, so attention scores emerge in the log2 domain with sign folded:
// softmax is exp2(s) directly for BOTH self and cross attends.

#define BB 4
#define NN 1024
#define CC 768
#define HH 12
#define HD 64

typedef unsigned short u16;
typedef short short8 __attribute__((ext_vector_type(8)));
typedef float f32x4 __attribute__((ext_vector_type(4)));

extern "C" __device__ float __ocml_native_exp2_f32(float);

__device__ __forceinline__ u16 f2bf(float f) {
  unsigned int u = __float_as_uint(f);
  return (u16)((u + 0x7fffu + ((u >> 16) & 1u)) >> 16);
}

__device__ __forceinline__ void load_lds16(const u16* g, u16* l) {
  __builtin_amdgcn_global_load_lds((__attribute__((address_space(1))) const void*)g,
                                   (__attribute__((address_space(3))) void*)l, 16, 0, 0);
}

// fp32 -> bf16 conversion: seg 0=x, 1=y, 2=w_qkv (query rows pre-scaled), 3=w_proj
__global__ __launch_bounds__(256)
void cvt_bf16(const float* __restrict__ x, const float* __restrict__ y,
              const float* __restrict__ wq, const float* __restrict__ wp,
              u16* __restrict__ xb, u16* __restrict__ yb,
              u16* __restrict__ wqb, u16* __restrict__ wpb)
{
  const int seg = blockIdx.y;
  const float* src = seg == 0 ? x : (seg == 1 ? y : (seg == 2 ? wq : wp));
  u16* dst = seg == 0 ? xb : (seg == 1 ? yb : (seg == 2 ? wqb : wpb));
  const int n = (seg == 3) ? 768 * 768 : ((seg == 2) ? 3072 * 768 : 4096 * 768);
  const int i = (blockIdx.x * 256 + threadIdx.x) * 8;
  if (i >= n) return;
  float sc = 1.0f;
  if (seg == 2) {
    const int row = i / 768;  // output feature p; j = p/768
    sc = (row < 768) ? -0.18033688f : (row < 1536 ? 0.18033688f : 1.0f);
  }
  float4 a = *(const float4*)(src + i);
  float4 b = *(const float4*)(src + i + 4);
  ushort4 u0 = {f2bf(a.x * sc), f2bf(a.y * sc), f2bf(a.z * sc), f2bf(a.w * sc)};
  ushort4 u1 = {f2bf(b.x * sc), f2bf(b.y * sc), f2bf(b.z * sc), f2bf(b.w * sc)};
  *(ushort4*)(dst + i) = u0;
  *(ushort4*)(dst + i + 4) = u1;
}

// MFMA GEMM v17 (= v14, best verified): C[m,p] = A[m,:] . W[p,:] (+bias).
// 128x128 tile, BK=64, 8 WAVES (512 thr) — wave owns a 64x32 sub-tile so
// acc[4][2] = 32 AGPRs (unified-file occupancy fix: 2 blocks/CU, 4 waves/SIMD).
// SINGLE-buffer 2-barrier staging: A/B chain v14=203.9, v15(dbuf+swz)=212.1,
// v16(dbuf)=210.1 -> explicit dbuf costs ~6 us here (m99/m100: implicit
// inter-wave overlap already hides the drain; prefetch cover of ~16 MFMAs is
// insufficient vs L3/HBM latency). XCD-chunk swizzle also regressed (~2 us):
// concurrent z-planes gave each XCD ~7.7 MB chunk footprint vs 4 MB L2.
// NZ1: column limit for blockIdx.z==1 (qkv_y's v-block j=3 is never read).
// VSPLIT: z==0, n0 in [2304,3072): epilogue writes VT directly (transposed +
// key-permuted, v11-verified) instead of C — vtrans prepass fused away.
template<int NP, bool BF16OUT, bool BIAS, int NZ1, bool VSPLIT>
__global__ __launch_bounds__(512, 4)
void gemm_mfma(const u16* __restrict__ A0, const u16* __restrict__ A1,
               const u16* __restrict__ W, const float* __restrict__ bias,
               void* __restrict__ C0, void* __restrict__ C1,
               u16* __restrict__ VTout)
{
  __shared__ u16 As[128 * 64];
  __shared__ u16 Bs[128 * 64];
  const int m0 = blockIdx.y * 128, n0 = blockIdx.x * 128;
  if (blockIdx.z && n0 >= NZ1) return;
  const u16* A = blockIdx.z ? A1 : A0;
  void* C = blockIdx.z ? C1 : C0;
  const int t = threadIdx.x, w = t >> 6, lane = t & 63;
  const int c = lane & 15, qq = lane >> 4;
  const int mq = (w >> 2) * 64, nq = (w & 3) * 32;  // wave -> 64x32 sub-tile

  const int lr = lane >> 3;
  const int lchunk = (lane & 7) ^ lr;
  int arow[2], brow[2];
#pragma unroll
  for (int i = 0; i < 2; i++) {
    const int r = (w * 2 + i) * 8 + lr;   // 16 segs x 8 rows = 128 rows
    arow[i] = (m0 + r) * 768 + lchunk * 8;
    brow[i] = (n0 + r) * 768 + lchunk * 8;
  }

  f32x4 acc[4][2] = {};
  for (int k0 = 0; k0 < 768; k0 += 64) {
    __syncthreads();
#pragma unroll
    for (int i = 0; i < 2; i++) {
      load_lds16(A + arow[i] + k0, As + (w * 2 + i) * 512);
      load_lds16(W + brow[i] + k0, Bs + (w * 2 + i) * 512);
    }
    __syncthreads();
#pragma unroll
    for (int s = 0; s < 2; s++) {
      const int swz = ((s * 4 + qq) ^ (c & 7)) * 8;
      short8 af[4], bf[2];
#pragma unroll
      for (int i = 0; i < 4; i++)
        af[i] = *(const short8*)&As[(mq + i * 16 + c) * 64 + swz];
#pragma unroll
      for (int j = 0; j < 2; j++)
        bf[j] = *(const short8*)&Bs[(nq + j * 16 + c) * 64 + swz];
#pragma unroll
      for (int i = 0; i < 4; i++)
#pragma unroll
        for (int j = 0; j < 2; j++)
          acc[i][j] = __builtin_amdgcn_mfma_f32_16x16x32_bf16(af[i], bf[j], acc[i][j], 0, 0, 0);
    }
  }

  if (VSPLIT && blockIdx.z == 0 && n0 >= 2304) {
    // v-block epilogue: transposed + key-permuted scatter into VT
#pragma unroll
    for (int i = 0; i < 4; i++)
#pragma unroll
      for (int r = 0; r < 4; r++) {
        const int m = m0 + mq + i * 16 + qq * 4 + r;       // b*1024 + key
        const int b_ = m >> 10, key = m & 1023;
        const int kt = key >> 5, kk = key & 31;
        const int mcol = kt * 32 + ((kk >> 2) & 3) * 8 + ((kk >> 4) & 1) * 4 + (kk & 3);
#pragma unroll
        for (int j = 0; j < 2; j++) {
          const int pl = n0 - 2304 + nq + c + j * 16;      // h*64 + d
          const int h_ = pl >> 6, d_ = pl & 63;
          VTout[(size_t)((b_ * HH + h_) * 64 + d_) * 1024 + mcol] = f2bf(acc[i][j][r]);
        }
      }
    return;
  }

  float bj[2] = {0.f, 0.f};
  if (BIAS) {
#pragma unroll
    for (int j = 0; j < 2; j++) bj[j] = bias[n0 + nq + c + j * 16];
  }
#pragma unroll
  for (int i = 0; i < 4; i++)
#pragma unroll
    for (int r = 0; r < 4; r++) {
      const size_t row = (size_t)(m0 + mq + i * 16 + qq * 4 + r) * NP + n0 + nq + c;
      if (BF16OUT) {
#pragma unroll
        for (int j = 0; j < 2; j++)
          ((u16*)C)[row + j * 16] = f2bf(acc[i][j][r]);
      } else {
#pragma unroll
        for (int j = 0; j < 2; j++)
          ((float*)C)[row + j * 16] = acc[i][j][r] + bj[j];
      }
    }
}

// MFMA attention v13 (unchanged, verified) — concat-P via key-permuted VT,
// K/VT double-buffer, 36864 B LDS pad capping 4 blocks/CU for per-XCD L2 fit
// (LOAD-BEARING: v11 showed >4 blocks/CU overflows 4MB L2 -> WRITE 63 MB),
// T5 setprio around the MFMA cluster.
__global__ __launch_bounds__(256, 4)
void attn_pair_mfma(const u16* __restrict__ qkvx, const u16* __restrict__ qkvy,
                    const u16* __restrict__ VT,
                    u16* __restrict__ sum_x, u16* __restrict__ sum_y)
{
  // 36864 B (occupancy cap). u16 layout: K0 [0,4096) K1 [4096,8192)
  // V0 [8192,12288) V1 [12288,16384); rest pad. Epilogue: Of 64x68 f32 alias.
  __shared__ __align__(16) u16 smem[18432];
  float (*Of)[68] = (float(*)[68])smem;

  // XCD-aware decode (perf heuristic only)
  const int blk = blockIdx.x;                // 1536 blocks
  const int xcd = blk & 7, slot = blk >> 3;  // 192 slots
  const int bh = (slot >> 5) * 8 + xcd;      // 6 groups x 8 = 48
  const int inner = slot & 31;
  const int qt = inner >> 1, pair = inner & 1;
  const int b = bh / HH, head = bh % HH;
  const u16* q1 = pair ? qkvy : qkvx;  // self q   (j=1, +scale folded)
  const u16* q2 = pair ? qkvx : qkvy;  // cross qo (j=0, -scale folded)
  const u16* ks = pair ? qkvy : qkvx;  // k (j=2)
  u16* outp = pair ? sum_y : sum_x;

  const int t = threadIdx.x, w = t >> 6, lane = t & 63;
  const int c = lane & 15, qq = lane >> 4;

  // Q B-frags (lane n=c holds q-row c of the wave's 16-row tile): 2 sets
  short8 Qf[2][2];
  {
    const int qrow = qt * 64 + w * 16 + c;
    const u16* qs = q1 + (size_t)(b * NN + qrow) * 3072 + CC + head * HD + qq * 8;
    const u16* qc = q2 + (size_t)(b * NN + qrow) * 3072 + head * HD + qq * 8;
    Qf[0][0] = *(const short8*)qs;
    Qf[0][1] = *(const short8*)(qs + 32);
    Qf[1][0] = *(const short8*)qc;
    Qf[1][1] = *(const short8*)(qc + 32);
  }

  const u16* kbase = ks + (size_t)(b * NN) * 3072 + 2 * CC + head * HD;
  const u16* vtb = VT + (size_t)(bh * 64) * 1024;

  const int lr = lane >> 3;
  const int sc8 = ((lane & 7) ^ lr) * 8;

  short8 ones;
#pragma unroll
  for (int i = 0; i < 8; i++) ones[i] = (short)0x3F80;  // bf16 1.0

  f32x4 O[2][4] = {};  // [set][t4]
  f32x4 L[2] = {};

  const int cx = c & 7;
  const int koff0 = (qq ^ cx) * 8;          // K/VT buffers: XOR staging layout
  const int koff1 = ((4 + qq) ^ cx) * 8;

  // prologue: stage tile 0 into buffer 0
#pragma unroll
  for (int i = 0; i < 2; i++) {
    const int r = (2 * w + i) * 8 + lr;
    load_lds16(kbase + (size_t)r * 3072 + sc8, smem + (2 * w + i) * 512);
    load_lds16(vtb + (size_t)r * 1024 + sc8, smem + 8192 + (2 * w + i) * 512);
  }
  __syncthreads();  // vmcnt(0) drain: tile 0 staged

  for (int c16 = 0; c16 < 16; ++c16) {
    const int cur = c16 & 1;
    const u16* Kb = smem + cur * 4096;
    const u16* Vb = smem + 8192 + cur * 4096;

    // issue next-tile staging before compute (latency hides under MFMA/exp2;
    // the end-of-iter barrier's implicit vmcnt(0) lands after compute)
    if (c16 < 15) {
      u16* Kn = smem + (cur ^ 1) * 4096;
      u16* Vn = smem + 8192 + (cur ^ 1) * 4096;
#pragma unroll
      for (int i = 0; i < 2; i++) {
        const int r = (2 * w + i) * 8 + lr;
        load_lds16(kbase + (size_t)((c16 + 1) * 64 + r) * 3072 + sc8,
                   Kn + (2 * w + i) * 512);
        load_lds16(vtb + (size_t)r * 1024 + (c16 + 1) * 64 + sc8,
                   Vn + (2 * w + i) * 512);
      }
    }

    __builtin_amdgcn_s_setprio(1);  // T5: favor this wave through the MFMA cluster

    // S^T per t4-tile for both sets; exp2 + pack kept in registers:
    // pk[s][t4][0] = keys (16t4+4qq+0, +1), pk[s][t4][1] = (+2, +3) as bf16x2
    unsigned pk[2][4][2];
#pragma unroll
    for (int t4 = 0; t4 < 4; t4++) {
      const u16* kr = Kb + (16 * t4 + c) * 64;
      short8 k0 = *(const short8*)(kr + koff0);
      short8 k1 = *(const short8*)(kr + koff1);
#pragma unroll
      for (int s = 0; s < 2; s++) {
        f32x4 z = {0.f, 0.f, 0.f, 0.f};
        z = __builtin_amdgcn_mfma_f32_16x16x32_bf16(k0, Qf[s][0], z, 0, 0, 0);
        z = __builtin_amdgcn_mfma_f32_16x16x32_bf16(k1, Qf[s][1], z, 0, 0, 0);
        unsigned int u0 = __float_as_uint(__ocml_native_exp2_f32(z[0]));
        unsigned int u1 = __float_as_uint(__ocml_native_exp2_f32(z[1]));
        unsigned int u2 = __float_as_uint(__ocml_native_exp2_f32(z[2]));
        unsigned int u3 = __float_as_uint(__ocml_native_exp2_f32(z[3]));
        pk[s][t4][0] = __builtin_amdgcn_perm(u1, u0, 0x07060302u);  // hi(u1)|hi(u0)
        pk[s][t4][1] = __builtin_amdgcn_perm(u3, u2, 0x07060302u);
      }
    }

    // PV A-frags by pure concatenation (k-slot j -> key 4qq+j / 16+4qq+j-4,
    // matched by the fused-epilogue VT column permutation). L via ones-MFMA.
    short8 pa[2][2];
#pragma unroll
    for (int s = 0; s < 2; s++) {
      union { unsigned u[4]; short8 s8; } f0, f1;
      f0.u[0] = pk[s][0][0]; f0.u[1] = pk[s][0][1];
      f0.u[2] = pk[s][1][0]; f0.u[3] = pk[s][1][1];
      f1.u[0] = pk[s][2][0]; f1.u[1] = pk[s][2][1];
      f1.u[2] = pk[s][3][0]; f1.u[3] = pk[s][3][1];
      pa[s][0] = f0.s8;
      pa[s][1] = f1.s8;
      L[s] = __builtin_amdgcn_mfma_f32_16x16x32_bf16(pa[s][0], ones, L[s], 0, 0, 0);
      L[s] = __builtin_amdgcn_mfma_f32_16x16x32_bf16(pa[s][1], ones, L[s], 0, 0, 0);
    }

    // PV
#pragma unroll
    for (int t4 = 0; t4 < 4; t4++) {
      const u16* vr = Vb + (16 * t4 + c) * 64;
      short8 v0 = *(const short8*)(vr + koff0);
      short8 v1 = *(const short8*)(vr + koff1);
#pragma unroll
      for (int s = 0; s < 2; s++) {
        O[s][t4] = __builtin_amdgcn_mfma_f32_16x16x32_bf16(pa[s][0], v0, O[s][t4], 0, 0, 0);
        O[s][t4] = __builtin_amdgcn_mfma_f32_16x16x32_bf16(pa[s][1], v1, O[s][t4], 0, 0, 0);
      }
    }

    __builtin_amdgcn_s_setprio(0);

    __syncthreads();  // all reads of buf[cur] done; buf[cur^1] staged
  }

  // loop-end barrier already synced all waves -> realias K/V region as Of
  float is[4], ic[4];
#pragma unroll
  for (int r = 0; r < 4; r++) {
    is[r] = 1.0f / L[0][r];
    ic[r] = 1.0f / L[1][r];
  }
#pragma unroll
  for (int t4 = 0; t4 < 4; t4++)
#pragma unroll
    for (int r = 0; r < 4; r++)
      Of[w * 16 + 4 * qq + r][16 * t4 + c] =
          O[0][t4][r] * is[r] + O[1][t4][r] * ic[r];
  __syncthreads();
  // out[b, qt*64+row, head*64+d] (bf16, coalesced)
#pragma unroll
  for (int p = 0; p < 4; p++) {
    const int idx = p * 256 + t;
    const int row = idx >> 4, c4 = (idx & 15) * 4;
    float4 v = *(const float4*)&Of[row][c4];
    ushort4 u = {f2bf(v.x), f2bf(v.y), f2bf(v.z), f2bf(v.w)};
    *(ushort4*)(outp + (size_t)(b * NN + qt * 64 + row) * CC + head * HD + c4) = u;
  }
}

extern "C" void kernel_launch(void* const* d_in, const int* in_sizes, int n_in,
                              void* d_out, int out_size, void* d_ws, size_t ws_size,
                              hipStream_t stream)
{
  const float* x      = (const float*)d_in[0];
  const float* y      = (const float*)d_in[1];
  const float* w_qkv  = (const float*)d_in[2];
  const float* w_proj = (const float*)d_in[3];
  const float* b_proj = (const float*)d_in[4];

  // ws layout (75.1 MB used):
  //   qkv_x 25.2 | qkv_y 25.2 | sum_x 6.3 (alias x_bf) | sum_y 6.3 (alias y_bf)
  //   | wq_bf 4.7 | wp_bf 1.2 | VT 6.3
  u16* qkv_x = (u16*)d_ws;
  u16* qkv_y = qkv_x + (size_t)4096 * 3072;
  u16* rest = qkv_y + (size_t)4096 * 3072;
  u16* sum_x = rest;
  u16* sum_y = sum_x + (size_t)4096 * 768;
  u16* x_bf  = rest;                       // aliases sum_x (dead after QKV)
  u16* y_bf  = x_bf + (size_t)4096 * 768;  // aliases sum_y
  u16* wq_bf = y_bf + (size_t)4096 * 768;
  u16* wp_bf = wq_bf + (size_t)3072 * 768;
  u16* VT    = wp_bf + (size_t)768 * 768;
  float* out_x = (float*)d_out;
  float* out_y = out_x + (size_t)4096 * 768;

  // 0) fp32 -> bf16 (w_qkv query rows pre-scaled by ±0.125·log2e)
  cvt_bf16<<<dim3(1536, 4), 256, 0, stream>>>(x, y, w_qkv, w_proj,
                                              x_bf, y_bf, wq_bf, wp_bf);

  // 1) QKV via MFMA: qkv_{x,y} = {x,y}_bf @ wq_bf^T (bf16 out).
  //    y skips its dead v-block (n0 >= 2304); x's v-block is written DIRECTLY
  //    to VT (transposed + key-permuted) — vtrans fused. 512-thread blocks.
  gemm_mfma<3072, true, false, 2304, true><<<dim3(24, 32, 2), 512, 0, stream>>>(
      x_bf, y_bf, wq_bf, nullptr, qkv_x, qkv_y, VT);

  // 2) paired MFMA attention -> sum_x, sum_y (bf16), XCD-swizzled 1-D grid
  attn_pair_mfma<<<dim3(1536), 256, 0, stream>>>(qkv_x, qkv_y, VT, sum_x, sum_y);

  // 3) out = sum @ wp_bf^T + b_proj (f32, MFMA), 512-thread blocks
  gemm_mfma<768, false, true, 768, false><<<dim3(6, 32, 2), 512, 0, stream>>>(
      sum_x, sum_y, wp_bf, b_proj, out_x, out_y, nullptr);
}